// Round 14
// baseline (59.487 us; speedup 1.0000x reference)
//
#include <hip/hip_runtime.h>

#define NTYPES 216
#define NPIX   4096
#define KD     576      // C*3*3
#define ROWLEN 577      // KD + bias
#define NPC    64       // pixels per block-iteration (1 iteration for all real buckets)
#define PSTR   640      // u16 elements per LDS row (576 data + 64 shift pad)

typedef __attribute__((ext_vector_type(8))) short short8;
typedef __attribute__((ext_vector_type(4))) float f32x4;
typedef __attribute__((ext_vector_type(4), aligned(4))) float f32x4u;  // 4B-aligned
typedef __attribute__((ext_vector_type(8))) unsigned short u16x8;
typedef __attribute__((ext_vector_type(4))) unsigned short u16x4;

static __device__ __forceinline__ unsigned short f2bf(float f) {
    unsigned u = __builtin_bit_cast(unsigned, f);
    unsigned r = (u + 0x7FFFu + ((u >> 16) & 1u)) >> 16;  // RNE
    return (unsigned short)r;
}

// ---------- Kernel A: blocks 0..255 grouped conv -> h (bf16); block 256 sort ----------
__global__ __launch_bounds__(256) void prep_kernel(
        const float* __restrict__ x, const float* __restrict__ w1,
        const float* __restrict__ b1, const int* __restrict__ buckets,
        unsigned short* __restrict__ hbf, int* __restrict__ offsets,
        int* __restrict__ sorted) {
    int tid = threadIdx.x;
    if (blockIdx.x == 256) {
        // ---- counting sort with parallel scan ----
        __shared__ int cnt[256];
        __shared__ int pre[256];
        cnt[tid] = 0;
        __syncthreads();
        for (int i = tid; i < NPIX; i += 256) atomicAdd(&cnt[buckets[i]], 1);
        __syncthreads();
        int v = cnt[tid];
        pre[tid] = v;
        __syncthreads();
        #pragma unroll
        for (int s = 1; s < 256; s <<= 1) {
            int add = (tid >= s) ? pre[tid - s] : 0;
            __syncthreads();
            pre[tid] += add;
            __syncthreads();
        }
        int excl = pre[tid] - v;            // exclusive prefix
        if (tid <= NTYPES) offsets[tid] = excl;
        cnt[tid] = excl;
        __syncthreads();
        for (int i = tid; i < NPIX; i += 256) {
            int b = buckets[i];
            sorted[atomicAdd(&cnt[b], 1)] = i;
        }
        return;
    }
    // ---- body1: grouped conv, 4 px/thread, store bf16 ----
    int flat = blockIdx.x * 256 + tid;   // c(6) | y(6) | x4(4)
    int x4 = flat & 15;
    int y  = (flat >> 4) & 63;
    int c  = flat >> 10;                  // block-uniform
    int g  = c >> 4;
    const float* wrow = w1 + c * 144;
    float o0, o1, o2, o3;
    o0 = o1 = o2 = o3 = b1[c];
    #pragma unroll
    for (int ci = 0; ci < 16; ++ci) {
        const float* xp = x + (g * 16 + ci) * 4096;
        #pragma unroll
        for (int dy = 0; dy < 3; ++dy) {
            int yy = y + dy - 1;
            if (yy < 0 || yy > 63) continue;
            const float* row = xp + yy * 64 + x4 * 4;
            f32x4 mm = *(const f32x4*)row;
            float xl = (x4 > 0)  ? row[-1] : 0.f;
            float xr = (x4 < 15) ? row[4]  : 0.f;
            float wa = wrow[ci * 9 + dy * 3 + 0];
            float wb = wrow[ci * 9 + dy * 3 + 1];
            float wc = wrow[ci * 9 + dy * 3 + 2];
            o0 = fmaf(wa, xl,    fmaf(wb, mm[0], fmaf(wc, mm[1], o0)));
            o1 = fmaf(wa, mm[0], fmaf(wb, mm[1], fmaf(wc, mm[2], o1)));
            o2 = fmaf(wa, mm[1], fmaf(wb, mm[2], fmaf(wc, mm[3], o2)));
            o3 = fmaf(wa, mm[2], fmaf(wb, mm[3], fmaf(wc, xr,    o3)));
        }
    }
    u16x4 r16;
    r16[0] = f2bf(fmaxf(o0, 0.f));
    r16[1] = f2bf(fmaxf(o1, 0.f));
    r16[2] = f2bf(fmaxf(o2, 0.f));
    r16[3] = f2bf(fmaxf(o3, 0.f));
    *(u16x4*)&hbf[flat * 4] = r16;
}

// ---------- Kernel B: per-bucket MFMA GEMM; W->LDS->regs, then LDS reused for P ----------
__global__ __launch_bounds__(512, 1) void dyn_kernel(
        const unsigned short* __restrict__ hbf, const float* __restrict__ emb,
        const float* __restrict__ w2, const float* __restrict__ b2,
        const float* __restrict__ x, const int* __restrict__ offsets,
        const int* __restrict__ sorted, float* __restrict__ out) {

    __shared__ alignas(16) unsigned short WP[64 * PSTR];   // 80 KB: W tile, then P tile
    __shared__ alignas(16) unsigned short Dl[NPC * 72];    //  9 KB intermediate
    __shared__ alignas(16) unsigned short w2l[64 * 72];    //  9 KB 1x1 weights bf16
    __shared__ float bias_l[64];
    __shared__ int pixs[NPC];

    int t = blockIdx.x;
    int start = offsets[t];
    int n = offsets[t + 1] - start;
    if (n <= 0) return;

    int tid  = threadIdx.x;
    int lane = tid & 63;
    int wv   = tid >> 6;
    int m    = wv & 3;          // M-tile (16 out channels)
    int ph2  = wv >> 2;         // pixel half-pair selector (0..1)
    int ra   = lane & 15;
    int kg   = lane >> 4;

    const float* eb = emb + (size_t)t * 36928;

    // ---- cooperative W stage: coalesced f32 loads, f2bf, ds_write_b128 ----
    #pragma unroll
    for (int it = 0; it < 9; ++it) {
        int u  = tid + it * 512;
        int r  = u / 72;
        int c0 = (u - r * 72) * 8;
        const float* src = eb + r * ROWLEN + c0;
        f32x4u a = *(const f32x4u*)src;
        f32x4u b = *(const f32x4u*)(src + 4);
        u16x8 v;
        #pragma unroll
        for (int j = 0; j < 4; ++j) { v[j] = f2bf(a[j]); v[j + 4] = f2bf(b[j]); }
        *(u16x8*)&WP[r * PSTR + (r & 7) * 8 + c0] = v;
    }
    if (tid < 64) bias_l[tid] = eb[tid * ROWLEN + KD];

    // stage w2 -> bf16 LDS (once)
    {
        int o = tid >> 3, i8 = (tid & 7) * 8;
        const float* src = w2 + o * 64 + i8;
        u16x8 v;
        #pragma unroll
        for (int j = 0; j < 8; ++j) v[j] = f2bf(src[j]);
        *(u16x8*)&w2l[o * 72 + i8] = v;
    }
    __syncthreads();   // W / w2 / bias ready

    // ---- pull W fragments into registers (once per block) ----
    int rowW = m * 16 + ra;
    const unsigned short* pW = WP + rowW * PSTR + (rowW & 7) * 8 + kg * 8;
    u16x8 Wr[9][2];
    #pragma unroll
    for (int ck = 0; ck < 9; ++ck) {
        Wr[ck][0] = *(const u16x8*)(pW + ck * 64);
        Wr[ck][1] = *(const u16x8*)(pW + ck * 64 + 32);
    }
    int ob0 = m * 16 + kg * 4;
    float bias0 = bias_l[ob0 + 0], bias1 = bias_l[ob0 + 1];
    float bias2 = bias_l[ob0 + 2], bias3 = bias_l[ob0 + 3];

    int q0 = ph2 * 2, q1 = ph2 * 2 + 1;   // this wave's two pixel quarters
    const unsigned short* pB0 = WP + (q0 * 16 + ra) * PSTR + (ra & 7) * 8 + kg * 8;
    const unsigned short* pB1 = WP + (q1 * 16 + ra) * PSTR + (ra & 7) * 8 + kg * 8;

    // gather roles: 8 threads per pixel slot
    int gp = tid >> 3;          // pixel slot 0..63
    int gk = tid & 7;           // k-octet 0..7
    unsigned short* pdst = WP + gp * PSTR + (gp & 7) * 8;

    for (int base = 0; base < n; base += NPC) {
        __syncthreads();   // protect WP (W-regs pulled / prev readers) + pixs + Dl
        if (tid < NPC) pixs[tid] = (base + tid < n) ? sorted[start + base + tid] : -1;
        __syncthreads();

        // ---- stage patch tile P[64 px][576 k] bf16 from hbf into WP ----
        {
            int pixel = pixs[gp];
            if (pixel >= 0) {
                int py = pixel >> 6, px = pixel & 63;
                #pragma unroll
                for (int pass = 0; pass < 9; ++pass) {
                    int k0 = pass * 64 + gk * 8;
                    u16x8 v;
                    #pragma unroll
                    for (int j = 0; j < 8; ++j) {
                        int k = k0 + j;
                        int cch = k / 9, r9 = k - cch * 9;
                        int dy = r9 / 3, dx = r9 - dy * 3;
                        unsigned short bits = 0;
                        int yy = py + dy - 1, xx = px + dx - 1;
                        if (yy >= 0 && yy < 64 && xx >= 0 && xx < 64)
                            bits = hbf[cch * 4096 + yy * 64 + xx];
                        v[j] = bits;
                    }
                    *(u16x8*)(pdst + k0) = v;
                }
            } else {
                u16x8 z = {0, 0, 0, 0, 0, 0, 0, 0};
                #pragma unroll
                for (int pass = 0; pass < 9; ++pass)
                    *(u16x8*)(pdst + pass * 64 + gk * 8) = z;
            }
        }
        __syncthreads();   // P ready

        // ---- K-loop: 18 ds_read_b128 x2 quarters + 36 MFMA ----
        f32x4 acc0 = {0.f, 0.f, 0.f, 0.f};
        f32x4 acc1 = {0.f, 0.f, 0.f, 0.f};
        #pragma unroll
        for (int ck = 0; ck < 9; ++ck) {
            #pragma unroll
            for (int ks = 0; ks < 2; ++ks) {
                u16x8 bv0 = *(const u16x8*)(pB0 + ck * 64 + ks * 32);
                u16x8 bv1 = *(const u16x8*)(pB1 + ck * 64 + ks * 32);
                acc0 = __builtin_amdgcn_mfma_f32_16x16x32_bf16(
                          __builtin_bit_cast(short8, Wr[ck][ks]),
                          __builtin_bit_cast(short8, bv0), acc0, 0, 0, 0);
                acc1 = __builtin_amdgcn_mfma_f32_16x16x32_bf16(
                          __builtin_bit_cast(short8, Wr[ck][ks]),
                          __builtin_bit_cast(short8, bv1), acc1, 0, 0, 0);
            }
        }

        // ---- bias + relu -> Dl (bf16), both quarters ----
        {
            int pi0 = q0 * 16 + ra, pi1 = q1 * 16 + ra;
            u16x4 dv0, dv1;
            dv0[0] = f2bf(fmaxf(acc0[0] + bias0, 0.f));
            dv0[1] = f2bf(fmaxf(acc0[1] + bias1, 0.f));
            dv0[2] = f2bf(fmaxf(acc0[2] + bias2, 0.f));
            dv0[3] = f2bf(fmaxf(acc0[3] + bias3, 0.f));
            dv1[0] = f2bf(fmaxf(acc1[0] + bias0, 0.f));
            dv1[1] = f2bf(fmaxf(acc1[1] + bias1, 0.f));
            dv1[2] = f2bf(fmaxf(acc1[2] + bias2, 0.f));
            dv1[3] = f2bf(fmaxf(acc1[3] + bias3, 0.f));
            *(u16x4*)&Dl[pi0 * 72 + ob0] = dv0;
            *(u16x4*)&Dl[pi1 * 72 + ob0] = dv1;
        }
        __syncthreads();   // D ready

        // ---- GEMM2: 1x1 conv (K=64), both quarters ----
        f32x4 acc2_0 = {0.f, 0.f, 0.f, 0.f};
        f32x4 acc2_1 = {0.f, 0.f, 0.f, 0.f};
        #pragma unroll
        for (int ks = 0; ks < 2; ++ks) {
            u16x8 a2 = *(const u16x8*)&w2l[(m * 16 + ra) * 72 + ks * 32 + kg * 8];
            u16x8 d0 = *(const u16x8*)&Dl[(q0 * 16 + ra) * 72 + ks * 32 + kg * 8];
            u16x8 d1 = *(const u16x8*)&Dl[(q1 * 16 + ra) * 72 + ks * 32 + kg * 8];
            acc2_0 = __builtin_amdgcn_mfma_f32_16x16x32_bf16(
                         __builtin_bit_cast(short8, a2),
                         __builtin_bit_cast(short8, d0), acc2_0, 0, 0, 0);
            acc2_1 = __builtin_amdgcn_mfma_f32_16x16x32_bf16(
                         __builtin_bit_cast(short8, a2),
                         __builtin_bit_cast(short8, d1), acc2_1, 0, 0, 0);
        }

        // ---- epilogue: + b2 + residual, relu, store (both quarters) ----
        {
            int pix0 = pixs[q0 * 16 + ra];
            int pix1 = pixs[q1 * 16 + ra];
            if (pix0 >= 0) {
                #pragma unroll
                for (int j = 0; j < 4; ++j) {
                    int o = ob0 + j;
                    float v = acc2_0[j] + b2[o] + x[o * 4096 + pix0];
                    out[o * 4096 + pix0] = fmaxf(v, 0.f);
                }
            }
            if (pix1 >= 0) {
                #pragma unroll
                for (int j = 0; j < 4; ++j) {
                    int o = ob0 + j;
                    float v = acc2_1[j] + b2[o] + x[o * 4096 + pix1];
                    out[o * 4096 + pix1] = fmaxf(v, 0.f);
                }
            }
        }
    }
}

extern "C" void kernel_launch(void* const* d_in, const int* in_sizes, int n_in,
                              void* d_out, int out_size, void* d_ws, size_t ws_size,
                              hipStream_t stream) {
    const float* x       = (const float*)d_in[0];
    const int*   buckets = (const int*)d_in[1];
    const float* w1      = (const float*)d_in[2];
    const float* b1      = (const float*)d_in[3];
    const float* emb     = (const float*)d_in[4];
    const float* w2      = (const float*)d_in[5];
    const float* b2      = (const float*)d_in[6];
    float* out = (float*)d_out;

    char* ws = (char*)d_ws;
    unsigned short* hbf = (unsigned short*)ws;              // 512 KB
    int*   offsets      = (int*)(ws + (1 << 20));           // 217 ints
    int*   sorted       = (int*)(ws + (1 << 20) + 4096);    // 4096 ints

    prep_kernel<<<257, 256, 0, stream>>>(x, w1, b1, buckets, hbf, offsets, sorted);
    dyn_kernel<<<NTYPES, 512, 0, stream>>>(hbf, emb, w2, b2, x, offsets, sorted, out);
}

// Round 15
// 37.758 us; speedup vs baseline: 1.5755x; 1.5755x over previous
//
#include <hip/hip_runtime.h>

#define NTYPES 216
#define NPIX   4096
#define KD     576      // C*3*3
#define ROWLEN 577      // KD + bias
#define NPC    32       // pixels per block-iteration
#define PSTR   640      // u16 elements per LDS row (576 data + 64 shift pad)

typedef __attribute__((ext_vector_type(8))) short short8;
typedef __attribute__((ext_vector_type(4))) float f32x4;
typedef __attribute__((ext_vector_type(4), aligned(4))) float f32x4u;  // 4B-aligned
typedef __attribute__((ext_vector_type(8))) unsigned short u16x8;
typedef __attribute__((ext_vector_type(4))) unsigned short u16x4;

static __device__ __forceinline__ unsigned short f2bf(float f) {
    unsigned u = __builtin_bit_cast(unsigned, f);
    unsigned r = (u + 0x7FFFu + ((u >> 16) & 1u)) >> 16;  // RNE
    return (unsigned short)r;
}

// ---------- Kernel A: blocks 0..255 grouped conv -> h (bf16); block 256 sort ----------
__global__ __launch_bounds__(256) void prep_kernel(
        const float* __restrict__ x, const float* __restrict__ w1,
        const float* __restrict__ b1, const int* __restrict__ buckets,
        unsigned short* __restrict__ hbf, int* __restrict__ offsets,
        int* __restrict__ sorted) {
    int tid = threadIdx.x;
    if (blockIdx.x == 256) {
        // ---- counting sort with parallel scan ----
        __shared__ int cnt[256];
        __shared__ int pre[256];
        cnt[tid] = 0;
        __syncthreads();
        for (int i = tid; i < NPIX; i += 256) atomicAdd(&cnt[buckets[i]], 1);
        __syncthreads();
        int v = cnt[tid];
        pre[tid] = v;
        __syncthreads();
        #pragma unroll
        for (int s = 1; s < 256; s <<= 1) {
            int add = (tid >= s) ? pre[tid - s] : 0;
            __syncthreads();
            pre[tid] += add;
            __syncthreads();
        }
        int excl = pre[tid] - v;            // exclusive prefix
        if (tid <= NTYPES) offsets[tid] = excl;
        cnt[tid] = excl;
        __syncthreads();
        for (int i = tid; i < NPIX; i += 256) {
            int b = buckets[i];
            sorted[atomicAdd(&cnt[b], 1)] = i;
        }
        return;
    }
    // ---- body1: grouped conv, 4 px/thread, store bf16 ----
    int flat = blockIdx.x * 256 + tid;   // c(6) | y(6) | x4(4)
    int x4 = flat & 15;
    int y  = (flat >> 4) & 63;
    int c  = flat >> 10;                  // block-uniform
    int g  = c >> 4;
    const float* wrow = w1 + c * 144;
    float o0, o1, o2, o3;
    o0 = o1 = o2 = o3 = b1[c];
    #pragma unroll
    for (int ci = 0; ci < 16; ++ci) {
        const float* xp = x + (g * 16 + ci) * 4096;
        #pragma unroll
        for (int dy = 0; dy < 3; ++dy) {
            int yy = y + dy - 1;
            if (yy < 0 || yy > 63) continue;
            const float* row = xp + yy * 64 + x4 * 4;
            f32x4 mm = *(const f32x4*)row;
            float xl = (x4 > 0)  ? row[-1] : 0.f;
            float xr = (x4 < 15) ? row[4]  : 0.f;
            float wa = wrow[ci * 9 + dy * 3 + 0];
            float wb = wrow[ci * 9 + dy * 3 + 1];
            float wc = wrow[ci * 9 + dy * 3 + 2];
            o0 = fmaf(wa, xl,    fmaf(wb, mm[0], fmaf(wc, mm[1], o0)));
            o1 = fmaf(wa, mm[0], fmaf(wb, mm[1], fmaf(wc, mm[2], o1)));
            o2 = fmaf(wa, mm[1], fmaf(wb, mm[2], fmaf(wc, mm[3], o2)));
            o3 = fmaf(wa, mm[2], fmaf(wb, mm[3], fmaf(wc, xr,    o3)));
        }
    }
    u16x4 r16;
    r16[0] = f2bf(fmaxf(o0, 0.f));
    r16[1] = f2bf(fmaxf(o1, 0.f));
    r16[2] = f2bf(fmaxf(o2, 0.f));
    r16[3] = f2bf(fmaxf(o3, 0.f));
    *(u16x4*)&hbf[flat * 4] = r16;
}

// ---------- Kernel B: per-bucket MFMA GEMM; W in LDS, A-fragments read in-loop ----------
__global__ __launch_bounds__(512) void dyn_kernel(
        const unsigned short* __restrict__ hbf, const float* __restrict__ emb,
        const float* __restrict__ w2, const float* __restrict__ b2,
        const float* __restrict__ x, const int* __restrict__ offsets,
        const int* __restrict__ sorted, float* __restrict__ out) {

    __shared__ alignas(16) unsigned short Wl[64 * PSTR];   // 80 KB  filter tile (bf16)
    __shared__ alignas(16) unsigned short Pl[NPC * PSTR];  // 40 KB  patches (bf16)
    __shared__ alignas(16) unsigned short Dl[NPC * 72];    //  4.5 KB intermediate
    __shared__ alignas(16) unsigned short w2l[64 * 72];    //  9 KB  1x1 weights bf16
    __shared__ float bias_l[64];
    __shared__ int pixs[NPC];

    int t = blockIdx.x;
    int start = offsets[t];
    int n = offsets[t + 1] - start;
    if (n <= 0) return;

    int tid  = threadIdx.x;
    int lane = tid & 63;
    int wv   = tid >> 6;
    int m    = wv & 3;          // M-tile (16 out channels)
    int ph   = wv >> 2;         // pixel half
    int ra   = lane & 15;
    int kg   = lane >> 4;

    const float* eb = emb + (size_t)t * 36928;

    // ---- cooperative W stage: coalesced f32 loads, f2bf, ds_write_b128 ----
    #pragma unroll
    for (int it = 0; it < 9; ++it) {
        int u  = tid + it * 512;
        int r  = u / 72;
        int c0 = (u - r * 72) * 8;
        const float* src = eb + r * ROWLEN + c0;
        f32x4u a = *(const f32x4u*)src;
        f32x4u b = *(const f32x4u*)(src + 4);
        u16x8 v;
        #pragma unroll
        for (int j = 0; j < 4; ++j) { v[j] = f2bf(a[j]); v[j + 4] = f2bf(b[j]); }
        *(u16x8*)&Wl[r * PSTR + (r & 7) * 8 + c0] = v;
    }
    if (tid < 64) bias_l[tid] = eb[tid * ROWLEN + KD];

    // stage w2 -> bf16 LDS (once)
    {
        int o = tid >> 3, i8 = (tid & 7) * 8;
        const float* src = w2 + o * 64 + i8;
        u16x8 v;
        #pragma unroll
        for (int j = 0; j < 8; ++j) v[j] = f2bf(src[j]);
        *(u16x8*)&w2l[o * 72 + i8] = v;
    }
    __syncthreads();   // W / w2 / bias ready

    int rowW = m * 16 + ra;
    const unsigned short* pA = Wl + rowW * PSTR + (rowW & 7) * 8 + kg * 8;
    int ob0 = m * 16 + kg * 4;
    float bias0 = bias_l[ob0 + 0], bias1 = bias_l[ob0 + 1];
    float bias2 = bias_l[ob0 + 2], bias3 = bias_l[ob0 + 3];

    const unsigned short* pB = Pl + (ph * 16 + ra) * PSTR + (ra & 7) * 8 + kg * 8;

    // gather roles
    int gp = tid >> 4;          // pixel 0..31
    int gk = tid & 15;
    unsigned short* pdst = Pl + gp * PSTR + (gp & 7) * 8;

    for (int base = 0; base < n; base += NPC) {
        __syncthreads();   // protect pixs/Pl/Dl from previous iteration's readers
        if (tid < NPC) pixs[tid] = (base + tid < n) ? sorted[start + base + tid] : -1;
        __syncthreads();

        // ---- stage patch tile P[32 px][576 k] bf16 from hbf ----
        {
            int pixel = pixs[gp];
            int py = pixel >> 6, px = pixel & 63;
            #pragma unroll
            for (int pass = 0; pass < 9; ++pass) {
                int k0 = pass * 64 + gk * 4;
                u16x4 v;
                #pragma unroll
                for (int j = 0; j < 4; ++j) {
                    int k = k0 + j;
                    int cch = k / 9, r9 = k - cch * 9;
                    int dy = r9 / 3, dx = r9 - dy * 3;
                    unsigned short bits = 0;
                    if (pixel >= 0) {
                        int yy = py + dy - 1, xx = px + dx - 1;
                        if (yy >= 0 && yy < 64 && xx >= 0 && xx < 64)
                            bits = hbf[cch * 4096 + yy * 64 + xx];
                    }
                    v[j] = bits;
                }
                *(u16x4*)(pdst + k0) = v;
            }
        }
        __syncthreads();   // P ready

        // ---- K-loop: 18 A-reads + 18 B-reads from LDS + 18 MFMA ----
        f32x4 acc = {0.f, 0.f, 0.f, 0.f};
        #pragma unroll
        for (int ck = 0; ck < 9; ++ck) {
            #pragma unroll
            for (int ks = 0; ks < 2; ++ks) {
                u16x8 av = *(const u16x8*)(pA + ck * 64 + ks * 32);
                u16x8 bv = *(const u16x8*)(pB + ck * 64 + ks * 32);
                acc = __builtin_amdgcn_mfma_f32_16x16x32_bf16(
                          __builtin_bit_cast(short8, av),
                          __builtin_bit_cast(short8, bv), acc, 0, 0, 0);
            }
        }

        // ---- bias + relu -> Dl (bf16) ----
        {
            int pi = ph * 16 + ra;
            u16x4 dv;
            dv[0] = f2bf(fmaxf(acc[0] + bias0, 0.f));
            dv[1] = f2bf(fmaxf(acc[1] + bias1, 0.f));
            dv[2] = f2bf(fmaxf(acc[2] + bias2, 0.f));
            dv[3] = f2bf(fmaxf(acc[3] + bias3, 0.f));
            *(u16x4*)&Dl[pi * 72 + ob0] = dv;
        }
        __syncthreads();   // D ready

        // ---- GEMM2: 1x1 conv (K=64) ----
        f32x4 acc2 = {0.f, 0.f, 0.f, 0.f};
        #pragma unroll
        for (int ks = 0; ks < 2; ++ks) {
            u16x8 a2  = *(const u16x8*)&w2l[(m * 16 + ra) * 72 + ks * 32 + kg * 8];
            u16x8 b2v = *(const u16x8*)&Dl[(ph * 16 + ra) * 72 + ks * 32 + kg * 8];
            acc2 = __builtin_amdgcn_mfma_f32_16x16x32_bf16(
                       __builtin_bit_cast(short8, a2),
                       __builtin_bit_cast(short8, b2v), acc2, 0, 0, 0);
        }

        // ---- epilogue: + b2 + residual, relu, store ----
        {
            int pi = ph * 16 + ra;
            int pixel = pixs[pi];
            if (pixel >= 0) {
                #pragma unroll
                for (int j = 0; j < 4; ++j) {
                    int o = ob0 + j;
                    float v = acc2[j] + b2[o] + x[o * 4096 + pixel];
                    out[o * 4096 + pixel] = fmaxf(v, 0.f);
                }
            }
        }
    }
}

extern "C" void kernel_launch(void* const* d_in, const int* in_sizes, int n_in,
                              void* d_out, int out_size, void* d_ws, size_t ws_size,
                              hipStream_t stream) {
    const float* x       = (const float*)d_in[0];
    const int*   buckets = (const int*)d_in[1];
    const float* w1      = (const float*)d_in[2];
    const float* b1      = (const float*)d_in[3];
    const float* emb     = (const float*)d_in[4];
    const float* w2      = (const float*)d_in[5];
    const float* b2      = (const float*)d_in[6];
    float* out = (float*)d_out;

    char* ws = (char*)d_ws;
    unsigned short* hbf = (unsigned short*)ws;              // 512 KB
    int*   offsets      = (int*)(ws + (1 << 20));           // 217 ints
    int*   sorted       = (int*)(ws + (1 << 20) + 4096);    // 4096 ints

    prep_kernel<<<257, 256, 0, stream>>>(x, w1, b1, buckets, hbf, offsets, sorted);
    dyn_kernel<<<NTYPES, 512, 0, stream>>>(hbf, emb, w2, b2, x, offsets, sorted, out);
}